// Round 1
// baseline (356.868 us; speedup 1.0000x reference)
//
#include <hip/hip_runtime.h>
#include <math.h>

// ---------------- problem constants (static shapes) ----------------
#define NIMG 8
#define ATOT 65472
#define KTOT 6960          // 2000+2000+2000+768+192
#define POST 2000
#define NMS_T 0.7f
#define TILES_PER_IMG 1668 // 528*3 + 78 + 6
#define MWORDS_PER_IMG 206400

__constant__ int c_NAPL[5]  = {49152,12288,3072,768,192};
__constant__ int c_LOFF[5]  = {0,49152,61440,64512,65280};
__constant__ int c_KSEL[5]  = {2000,2000,2000,768,192};
__constant__ int c_CBASE[5] = {0,2000,4000,6000,6768};
__constant__ int c_GLVL[5]  = {32,32,32,12,3};      // ceil(k/64)
__constant__ int c_SORTM[5] = {2048,2048,2048,1024,256};
__constant__ int c_TILEPFX[6] = {0,528,1056,1584,1662,1668};
__constant__ int c_MOFFL[5] = {0,65536,131072,196608,205824}; // u64-word offsets within image

// monotone float->uint map (order-preserving for all finite floats)
__device__ __forceinline__ unsigned f2u(float f){
  unsigned b = __float_as_uint(f);
  return (b & 0x80000000u) ? ~b : (b | 0x80000000u);
}
// composite key: (value desc, global idx asc) when sorted descending
__device__ __forceinline__ unsigned long long mkkey(unsigned u, unsigned gidx){
  return ((unsigned long long)u << 32) | (unsigned long long)(0xFFFFFFFFu - gidx);
}

// in-LDS bitonic sort, descending, m = power of two
__device__ void bitonic_desc(unsigned long long* sb, int m){
  int tid = threadIdx.x, nthr = blockDim.x;
  for (int size = 2; size <= m; size <<= 1){
    for (int stride = size >> 1; stride > 0; stride >>= 1){
      __syncthreads();
      for (int t = tid; t < (m >> 1); t += nthr){
        int lo = t & (stride - 1);
        int i  = ((t - lo) << 1) + lo;
        int j  = i + stride;
        bool desc = ((i & size) == 0);
        unsigned long long a = sb[i], b = sb[j];
        if (desc ? (a < b) : (a > b)) { sb[i] = b; sb[j] = a; }
      }
    }
  }
  __syncthreads();
}

// ---------------- K1: per-(img,lvl) top-k select + sort + box prep ----------------
extern "C" __global__ void __launch_bounds__(1024)
k_select(const float* __restrict__ prop, const float* __restrict__ obj,
         unsigned long long* __restrict__ cand, float4* __restrict__ cbox){
  __shared__ unsigned long long sb[2048];
  __shared__ unsigned hist[256];
  __shared__ unsigned s_pfx, s_rem, s_cnt;
  int task = blockIdx.x, img = task / 5, lvl = task % 5;
  int n = c_NAPL[lvl], off = c_LOFF[lvl], k = c_KSEL[lvl], m = c_SORTM[lvl];
  const float* o = obj + (size_t)img * ATOT;
  int tid = threadIdx.x;

  if (k == n){
    // small levels: take everything
    for (int i = tid; i < n; i += blockDim.x){
      unsigned gidx = (unsigned)(off + i);
      sb[i] = mkkey(f2u(o[gidx]), gidx);
    }
    for (int i = n + tid; i < m; i += blockDim.x) sb[i] = 0ull;
  } else {
    // radix-select exact 32-bit threshold T of the k-th largest u
    if (tid == 0){ s_pfx = 0u; s_rem = (unsigned)k; }
    for (int round = 0; round < 4; ++round){
      int shift = 24 - 8 * round;
      for (int i = tid; i < 256; i += blockDim.x) hist[i] = 0u;
      __syncthreads();
      unsigned pfx = s_pfx;
      for (int i = tid; i < n; i += blockDim.x){
        unsigned u = f2u(o[off + i]);
        if (round == 0 || (u >> (shift + 8)) == pfx)
          atomicAdd(&hist[(u >> shift) & 255u], 1u);
      }
      __syncthreads();
      if (tid == 0){
        unsigned rem = s_rem, c = 0u;
        for (int b = 255; b >= 0; --b){
          c += hist[b];
          if (c >= rem){ s_rem = rem - (c - hist[b]); s_pfx = (pfx << 8) | (unsigned)b; break; }
        }
      }
      __syncthreads();
    }
    unsigned T = s_pfx;
    if (tid == 0) s_cnt = 0u;
    __syncthreads();
    // append all u >= T; sorting composite keys resolves threshold ties by idx asc,
    // taking first k after the sort == exact top-k (value desc, idx asc)
    for (int i = tid; i < n; i += blockDim.x){
      unsigned u = f2u(o[off + i]);
      if (u >= T){
        unsigned p = atomicAdd(&s_cnt, 1u);
        if (p < 2048u) sb[p] = mkkey(u, (unsigned)(off + i));
      }
    }
    __syncthreads();
    unsigned cnt = min(s_cnt, 2048u);
    for (int i = (int)cnt + tid; i < m; i += blockDim.x) sb[i] = 0ull;
  }

  bitonic_desc(sb, m);

  // write sorted candidate keys + clipped boxes
  const float* pr = prop + (size_t)img * ATOT * 4;
  for (int i = tid; i < k; i += blockDim.x){
    unsigned long long key = sb[i];
    size_t slot = (size_t)img * KTOT + c_CBASE[lvl] + i;
    cand[slot] = key;
    unsigned gidx = 0xFFFFFFFFu - (unsigned)(key & 0xFFFFFFFFull);
    const float* p = pr + (size_t)gidx * 4;
    float x1 = fminf(fmaxf(p[0], 0.f), 512.f);
    float y1 = fminf(fmaxf(p[1], 0.f), 512.f);
    float x2 = fminf(fmaxf(p[2], 0.f), 512.f);
    float y2 = fminf(fmaxf(p[3], 0.f), 512.f);
    cbox[slot] = make_float4(x1, y1, x2, y2);
  }
  // note: min-size/score filters are provably vacuous for this input domain
  // (w,h >= 2, centers in [0,512] => clipped w,h >= 1; sigmoid >= 0 = thresh)
}

// ---------------- K2a: parallel suppression-bitmask matrix ----------------
extern "C" __global__ void __launch_bounds__(64)
k_mask(const float4* __restrict__ cbox, unsigned long long* __restrict__ mask,
       unsigned long long* __restrict__ rowAny){
  __shared__ float4 colb[64];
  __shared__ float  colarea[64];
  int bid = blockIdx.x;
  int img = bid / TILES_PER_IMG, r = bid % TILES_PER_IMG;
  int lvl = 0;
  while (r >= c_TILEPFX[lvl + 1]) ++lvl;
  int t = r - c_TILEPFX[lvl];
  int G = c_GLVL[lvl], k = c_KSEL[lvl];
  int gi = 0;
  while (t >= G - gi){ t -= G - gi; ++gi; }
  int gj = gi + t;
  int lane = threadIdx.x;
  const float4* cb = cbox + (size_t)img * KTOT + c_CBASE[lvl];

  int jj = gj * 64 + lane;
  float4 bb = (jj < k) ? cb[jj] : make_float4(0.f, 0.f, 0.f, 0.f);
  colb[lane] = bb;
  colarea[lane] = (bb.z - bb.x) * (bb.w - bb.y);
  __syncthreads();

  int i = gi * 64 + lane;
  if (i < k){
    float4 a = cb[i];
    float aarea = (a.z - a.x) * (a.w - a.y);
    unsigned long long word = 0ull;
    int j0 = (gi == gj) ? (lane + 1) : 0;
    int jmax = min(64, k - gj * 64);
    for (int j = j0; j < jmax; ++j){
      float4 b = colb[j];
      float ix = fminf(a.z, b.z) - fmaxf(a.x, b.x);
      if (ix > 0.f){
        float iy = fminf(a.w, b.w) - fmaxf(a.y, b.y);
        if (iy > 0.f){
          float inter = ix * iy;
          float uni = aarea + colarea[j] - inter;
          if (inter / uni > NMS_T) word |= (1ull << j);  // division to match ref rounding
        }
      }
    }
    size_t mo = (size_t)img * MWORDS_PER_IMG + (size_t)c_MOFFL[lvl] + (size_t)i * G + gj;
    mask[mo] = word;
    if (word){
      int taskid = img * 5 + lvl;
      atomicOr(&rowAny[taskid * 32 + gi], 1ull << lane);
    }
  }
}

// ---------------- K2b: exact greedy NMS scan (nonzero rows only) ----------------
extern "C" __global__ void __launch_bounds__(64)
k_scan(const unsigned long long* __restrict__ cand, const unsigned long long* __restrict__ mask,
       const unsigned long long* __restrict__ rowAny, unsigned long long* __restrict__ keep){
  int task = blockIdx.x, img = task / 5, lvl = task % 5;
  int k = c_KSEL[lvl], G = c_GLVL[lvl];
  const unsigned long long* mbase = mask + (size_t)img * MWORDS_PER_IMG + c_MOFFL[lvl];
  int lane = threadIdx.x;
  unsigned long long remv = 0ull;   // lane l (< G) holds removed-bitmap word l
  for (int w = 0; w < G; ++w){
    unsigned long long bits = rowAny[task * 32 + w];   // uniform
    while (bits){
      int b = __ffsll((unsigned long long)bits) - 1; bits &= bits - 1;
      unsigned long long rw = __shfl(remv, w);
      if (!((rw >> b) & 1ull)){                        // row still kept -> it suppresses
        int i = w * 64 + b;
        if (lane >= w && lane < G) remv |= mbase[(size_t)i * G + lane];
      }
    }
  }
  for (int i = lane; i < k; i += 64){
    unsigned long long rw = __shfl(remv, i >> 6);
    bool kept = !((rw >> (i & 63)) & 1ull);
    size_t slot = (size_t)img * KTOT + c_CBASE[lvl] + i;
    keep[slot] = kept ? cand[slot] : 0ull;
  }
}

// ---------------- K3: per-image merge (sort kept keys) + output ----------------
extern "C" __global__ void __launch_bounds__(1024)
k_merge(const float* __restrict__ prop, const float* __restrict__ obj,
        const unsigned long long* __restrict__ keep, float* __restrict__ out){
  __shared__ unsigned long long sb[8192];   // 64 KB
  int img = blockIdx.x, tid = threadIdx.x;
  for (int i = tid; i < KTOT; i += blockDim.x) sb[i] = keep[(size_t)img * KTOT + i];
  for (int i = KTOT + tid; i < 8192; i += blockDim.x) sb[i] = 0ull;
  bitonic_desc(sb, 8192);
  const float* pr = prop + (size_t)img * ATOT * 4;
  const float* o  = obj  + (size_t)img * ATOT;
  float* ob = out + (size_t)img * POST * 4;
  float* os = out + (size_t)NIMG * POST * 4 + (size_t)img * POST;
  for (int i = tid; i < POST; i += blockDim.x){
    unsigned long long key = sb[i];
    if (key){
      unsigned gidx = 0xFFFFFFFFu - (unsigned)(key & 0xFFFFFFFFull);
      const float* p = pr + (size_t)gidx * 4;
      ob[i * 4 + 0] = fminf(fmaxf(p[0], 0.f), 512.f);
      ob[i * 4 + 1] = fminf(fmaxf(p[1], 0.f), 512.f);
      ob[i * 4 + 2] = fminf(fmaxf(p[2], 0.f), 512.f);
      ob[i * 4 + 3] = fminf(fmaxf(p[3], 0.f), 512.f);
      double s = 1.0 / (1.0 + exp(-(double)o[gidx]));  // correctly-rounded f32 sigmoid
      os[i] = (float)s;
    } else {
      ob[i * 4 + 0] = 0.f; ob[i * 4 + 1] = 0.f; ob[i * 4 + 2] = 0.f; ob[i * 4 + 3] = 0.f;
      os[i] = 0.f;
    }
  }
}

// ---------------- launch ----------------
extern "C" void kernel_launch(void* const* d_in, const int* in_sizes, int n_in,
                              void* d_out, int out_size, void* d_ws, size_t ws_size,
                              hipStream_t stream){
  const float* prop = (const float*)d_in[0];
  const float* obj  = (const float*)d_in[1];
  char* ws = (char*)d_ws;
  // ws layout (bytes):
  unsigned long long* cand   = (unsigned long long*)(ws);            // 8*6960*8   = 445440
  float4*             cbox   = (float4*)(ws + 445440);               // 8*6960*16  = 890880 -> 1336320
  unsigned long long* keep   = (unsigned long long*)(ws + 1336320);  // 445440 -> 1781760
  unsigned long long* rowAny = (unsigned long long*)(ws + 1781760);  // 40*32*8 = 10240 -> 1792000
  unsigned long long* mask   = (unsigned long long*)(ws + 1792000);  // 8*206400*8 = 13209600 -> ~15.0 MB

  hipMemsetAsync(rowAny, 0, 40 * 32 * 8, stream);
  hipLaunchKernelGGL(k_select, dim3(40), dim3(1024), 0, stream, prop, obj, cand, cbox);
  hipLaunchKernelGGL(k_mask,  dim3(NIMG * TILES_PER_IMG), dim3(64), 0, stream, cbox, mask, rowAny);
  hipLaunchKernelGGL(k_scan,  dim3(40), dim3(64), 0, stream, cand, mask, rowAny, keep);
  hipLaunchKernelGGL(k_merge, dim3(NIMG), dim3(1024), 0, stream, prop, obj, keep, (float*)d_out);
}